// Round 1
// baseline (633.026 us; speedup 1.0000x reference)
//
#include <hip/hip_runtime.h>
#include <hip/hip_bf16.h>

// ---------- types ----------
typedef short  bf16x8s __attribute__((ext_vector_type(8)));  // 8 bf16 (4 VGPRs)
typedef float  f32x4   __attribute__((ext_vector_type(4)));  // 4 fp32 acc

// Sizes (compile-time for this problem)
#define BATCH 32
#define SEQL  2048
#define NROWS (BATCH * SEQL)   // 65536
#define IN    1024
#define HID   1024

#define BM 128
#define BN 128
#define BK 32

// pack two fp32 -> two bf16 (round half-away via +0x8000, then v_perm byte select)
__device__ __forceinline__ unsigned int pack2bf(float f0, float f1) {
    unsigned int u0 = __float_as_uint(f0) + 0x8000u;
    unsigned int u1 = __float_as_uint(f1) + 0x8000u;
    // result bytes [0,1] = u0 bytes [2,3]; bytes [2,3] = u1 bytes [2,3]
    return __builtin_amdgcn_perm(u1, u0, 0x07060302u);
}

__device__ __forceinline__ float tanh_fast(float x) {
    float xc = fminf(fmaxf(x, -15.f), 15.f);
    float t  = __builtin_amdgcn_exp2f(xc * 2.8853900817779268f); // e^(2x)
    return (t - 1.f) * __builtin_amdgcn_rcpf(t + 1.f);
}

// ---------- kernel 1: convert W_h (first 1024 cols of ln_w) to bf16 ----------
__global__ __launch_bounds__(256) void convw_kernel(const float* __restrict__ ln_w,
                                                    unsigned short* __restrict__ whb) {
    const int n = blockIdx.x;
    const int t = threadIdx.x;
    float4 v = ((const float4*)(ln_w + (size_t)n * 2048))[t];
    uint2 pk;
    pk.x = pack2bf(v.x, v.y);
    pk.y = pack2bf(v.z, v.w);
    *(uint2*)(whb + (size_t)n * 1024 + t * 4) = pk;
}

// ---------- kernel 2: bias = ln_b + W_vq @ vq ----------
__global__ __launch_bounds__(256) void bias_kernel(const float* __restrict__ ln_w,
                                                   const float* __restrict__ ln_b,
                                                   const float* __restrict__ vq,
                                                   float* __restrict__ bias) {
    const int wave = threadIdx.x >> 6;
    const int lane = threadIdx.x & 63;
    const int n = blockIdx.x * 4 + wave;
    const float* wrow = ln_w + (size_t)n * 2048 + 1024;
    float sum = 0.f;
    #pragma unroll
    for (int j = 0; j < 16; ++j) {
        int k = lane + j * 64;
        sum += wrow[k] * vq[k];
    }
    #pragma unroll
    for (int off = 32; off; off >>= 1) sum += __shfl_xor(sum, off);
    if (lane == 0) bias[n] = ln_b[n] + sum;
}

// ---------- kernel 3: fused GEMM (h @ W_h^T + bias) -> tanh -> dot v_w -> s ----------
__global__ __launch_bounds__(256) void gemm_tanh_kernel(const float* __restrict__ hmat,
                                                        const unsigned short* __restrict__ whb,
                                                        const float* __restrict__ bias,
                                                        const float* __restrict__ vw,
                                                        float* __restrict__ s_buf) {
    __shared__ __align__(16) unsigned short As[BM * BK]; // 8 KB, XOR-swizzled
    __shared__ __align__(16) unsigned short Bs[BN * BK]; // 8 KB, XOR-swizzled

    const int tid  = threadIdx.x;
    const int cb   = blockIdx.x & 7;   // col block fastest: 8 siblings co-temporal, LIC absorbs A re-reads
    const int rb   = blockIdx.x >> 3;
    const int wave = tid >> 6;
    const int lane = tid & 63;
    const int quad = lane >> 4;
    const int l15  = lane & 15;
    const int wy   = wave >> 1;
    const int wx   = wave & 1;
    const int row0 = rb * BM;
    const int col0 = cb * BN;

    // staging: thread owns 8-float group (row = tid>>2, g = tid&3) and the row+64 twin
    const int srow = tid >> 2;
    const int sg   = tid & 3;
    const int swz  = (srow >> 1) & 3;                 // same for srow and srow+64
    const float*          gA0 = hmat + (size_t)(row0 + srow)      * 1024 + sg * 8;
    const float*          gA1 = hmat + (size_t)(row0 + srow + 64) * 1024 + sg * 8;
    const unsigned short* gB0 = whb  + (size_t)(col0 + srow)      * 1024 + sg * 8;
    const unsigned short* gB1 = gB0 + (size_t)64 * 1024;
    unsigned short* wA0 = As + srow * 32 + ((sg ^ swz) * 8);
    unsigned short* wA1 = wA0 + 64 * 32;
    unsigned short* wB0 = Bs + srow * 32 + ((sg ^ swz) * 8);
    unsigned short* wB1 = wB0 + 64 * 32;

    // fragment read pointers (k-invariant; swizzled slot = quad ^ ((row>>1)&3))
    const unsigned short* rA[4];
    const unsigned short* rB[4];
    #pragma unroll
    for (int i = 0; i < 4; ++i) {
        int ra = wy * 64 + i * 16 + l15;
        rA[i] = As + ra * 32 + ((quad ^ ((ra >> 1) & 3)) * 8);
        int rn = wx * 64 + i * 16 + l15;
        rB[i] = Bs + rn * 32 + ((quad ^ ((rn >> 1) & 3)) * 8);
    }

    f32x4 acc[4][4];
    #pragma unroll
    for (int i = 0; i < 4; ++i)
        #pragma unroll
        for (int j = 0; j < 4; ++j)
            acc[i][j] = (f32x4){0.f, 0.f, 0.f, 0.f};

    for (int k0 = 0; k0 < 1024; k0 += BK) {
        // issue global loads early (overlap previous iter's MFMAs)
        float4 va0 = *(const float4*)(gA0 + k0);
        float4 va1 = *(const float4*)(gA0 + k0 + 4);
        float4 va2 = *(const float4*)(gA1 + k0);
        float4 va3 = *(const float4*)(gA1 + k0 + 4);
        uint4  vb0 = *(const uint4*)(gB0 + k0);
        uint4  vb1 = *(const uint4*)(gB1 + k0);

        __syncthreads();   // previous tile's frag reads complete

        uint4 pa0, pa1;
        pa0.x = pack2bf(va0.x, va0.y); pa0.y = pack2bf(va0.z, va0.w);
        pa0.z = pack2bf(va1.x, va1.y); pa0.w = pack2bf(va1.z, va1.w);
        pa1.x = pack2bf(va2.x, va2.y); pa1.y = pack2bf(va2.z, va2.w);
        pa1.z = pack2bf(va3.x, va3.y); pa1.w = pack2bf(va3.z, va3.w);
        *(uint4*)wA0 = pa0;
        *(uint4*)wA1 = pa1;
        *(uint4*)wB0 = vb0;
        *(uint4*)wB1 = vb1;

        __syncthreads();   // staging visible

        bf16x8s af[4], bfv[4];
        #pragma unroll
        for (int i = 0; i < 4; ++i) af[i]  = *(const bf16x8s*)rA[i];
        #pragma unroll
        for (int i = 0; i < 4; ++i) bfv[i] = *(const bf16x8s*)rB[i];
        #pragma unroll
        for (int mt = 0; mt < 4; ++mt)
            #pragma unroll
            for (int nt = 0; nt < 4; ++nt)
                acc[mt][nt] = __builtin_amdgcn_mfma_f32_16x16x32_bf16(af[mt], bfv[nt], acc[mt][nt], 0, 0, 0);
    }

    // ---- epilogue: s_partial[row] = sum_cols tanh(pre + bias) * v_w ----
    // C/D layout: col = lane&15, row = quad*4 + r   [measured m89/m91]
    const int colb = col0 + wx * 64 + l15;
    float vwv[4], bv[4];
    #pragma unroll
    for (int nt = 0; nt < 4; ++nt) {
        vwv[nt] = vw[colb + nt * 16];
        bv[nt]  = bias[colb + nt * 16];
    }
    const int rowb = row0 + wy * 64 + quad * 4;
    #pragma unroll
    for (int mt = 0; mt < 4; ++mt) {
        #pragma unroll
        for (int r = 0; r < 4; ++r) {
            float p = 0.f;
            #pragma unroll
            for (int nt = 0; nt < 4; ++nt)
                p += tanh_fast(acc[mt][nt][r] + bv[nt]) * vwv[nt];
            // reduce across the 16 lanes (different cols, same row)
            p += __shfl_xor(p, 1);
            p += __shfl_xor(p, 2);
            p += __shfl_xor(p, 4);
            p += __shfl_xor(p, 8);
            if (l15 == 0) atomicAdd(&s_buf[rowb + mt * 16 + r], p);
        }
    }
}

// ---------- kernel 4: masked softmax over L per batch ----------
__global__ __launch_bounds__(256) void softmax_kernel(const float* __restrict__ s_buf,
                                                      const int* __restrict__ mask,
                                                      float* __restrict__ a_buf) {
    const int b    = blockIdx.x;
    const int t    = threadIdx.x;
    const int wave = t >> 6;
    const int lane = t & 63;
    __shared__ float redm[4];
    __shared__ float reds[4];
    float sv[8];
    float mx = -3.0e38f;
    #pragma unroll
    for (int j = 0; j < 8; ++j) {
        int l = t + j * 256;
        float v = s_buf[b * 2048 + l];
        if (mask[b * 2048 + l] == 0) v -= 10000.f;
        sv[j] = v;
        mx = fmaxf(mx, v);
    }
    #pragma unroll
    for (int off = 32; off; off >>= 1) mx = fmaxf(mx, __shfl_xor(mx, off));
    if (lane == 0) redm[wave] = mx;
    __syncthreads();
    mx = fmaxf(fmaxf(redm[0], redm[1]), fmaxf(redm[2], redm[3]));
    float sum = 0.f;
    #pragma unroll
    for (int j = 0; j < 8; ++j) {
        sv[j] = __expf(sv[j] - mx);
        sum += sv[j];
    }
    #pragma unroll
    for (int off = 32; off; off >>= 1) sum += __shfl_xor(sum, off);
    if (lane == 0) reds[wave] = sum;
    __syncthreads();
    sum = reds[0] + reds[1] + reds[2] + reds[3];
    float inv = 1.f / sum;
    #pragma unroll
    for (int j = 0; j < 8; ++j)
        a_buf[b * 2048 + t + j * 256] = sv[j] * inv;
}

// ---------- kernel 5: r[b,i] = sum_l a[b,l] * h[b,l,i] ----------
__global__ __launch_bounds__(256) void r_kernel(const float* __restrict__ hmat,
                                                const float* __restrict__ a_buf,
                                                float* __restrict__ out) {
    const int b  = blockIdx.x >> 4;
    const int lc = blockIdx.x & 15;
    const int t  = threadIdx.x;
    __shared__ float aw[128];
    if (t < 128) aw[t] = a_buf[b * 2048 + lc * 128 + t];
    __syncthreads();
    const float4* hp = (const float4*)hmat + (size_t)(b * 2048 + lc * 128) * 256;
    float ax = 0.f, ay = 0.f, az = 0.f, aq = 0.f;
    #pragma unroll 4
    for (int l = 0; l < 128; ++l) {
        float4 hv = hp[(size_t)l * 256 + t];
        float av = aw[l];
        ax += av * hv.x; ay += av * hv.y; az += av * hv.z; aq += av * hv.w;
    }
    float* op = out + b * 1024 + t * 4;
    atomicAdd(op + 0, ax);
    atomicAdd(op + 1, ay);
    atomicAdd(op + 2, az);
    atomicAdd(op + 3, aq);
}

// ---------- launch ----------
extern "C" void kernel_launch(void* const* d_in, const int* in_sizes, int n_in,
                              void* d_out, int out_size, void* d_ws, size_t ws_size,
                              hipStream_t stream) {
    const float* h    = (const float*)d_in[0];
    const int*   mask = (const int*)d_in[1];   // bool -> int32 per harness convention
    const float* ln_w = (const float*)d_in[2];
    const float* ln_b = (const float*)d_in[3];
    const float* v_w  = (const float*)d_in[4];
    const float* vq   = (const float*)d_in[5];
    float* out = (float*)d_out;

    char* ws = (char*)d_ws;
    unsigned short* whb  = (unsigned short*)ws;                       // 2 MB  bf16 W_h
    float* bias          = (float*)(ws + 2097152);                    // 4 KB
    float* s_buf         = (float*)(ws + 2097152 + 4096);             // 256 KB
    float* a_buf         = (float*)(ws + 2097152 + 4096 + 262144);    // 256 KB

    hipMemsetAsync(s_buf, 0, NROWS * sizeof(float), stream);
    hipMemsetAsync(d_out, 0, (size_t)out_size * sizeof(float), stream);

    convw_kernel<<<1024, 256, 0, stream>>>(ln_w, whb);
    bias_kernel<<<256, 256, 0, stream>>>(ln_w, ln_b, vq, bias);
    gemm_tanh_kernel<<<(NROWS / BM) * (HID / BN), 256, 0, stream>>>(h, whb, bias, v_w, s_buf);
    softmax_kernel<<<BATCH, 256, 0, stream>>>(s_buf, mask, a_buf);
    r_kernel<<<BATCH * 16, 256, 0, stream>>>(h, a_buf, out);
}

// Round 2
// 608.515 us; speedup vs baseline: 1.0403x; 1.0403x over previous
//
#include <hip/hip_runtime.h>
#include <hip/hip_bf16.h>

// ---------- types ----------
typedef short  bf16x8s __attribute__((ext_vector_type(8)));  // 8 bf16 (4 VGPRs)
typedef float  f32x4   __attribute__((ext_vector_type(4)));  // 4 fp32 acc

#define BATCH 32
#define SEQL  2048
#define NROWS (BATCH * SEQL)   // 65536
#define IN    1024
#define HID   1024

#define BM 128
#define BN 128
#define BK 32

// workspace layout
#define WHB_OFF   0u          // 2 MB  bf16 W_h
#define BIAS_OFF  0x200000u   // 4 KB
#define SBUF_OFF  0x210000u   // 256 KB
#define ABUF_OFF  0x250000u   // 256 KB
#define HB_OFF    0x290000u   // 128 MB bf16 h (optional)
#define WS_NEED_BF16 ((size_t)HB_OFF + (size_t)NROWS * IN * 2)

// pack two fp32 -> two bf16 (round-up-on-half via +0x8000, v_perm byte select)
__device__ __forceinline__ unsigned int pack2bf(float f0, float f1) {
    unsigned int u0 = __float_as_uint(f0) + 0x8000u;
    unsigned int u1 = __float_as_uint(f1) + 0x8000u;
    return __builtin_amdgcn_perm(u1, u0, 0x07060302u);
}

__device__ __forceinline__ float tanh_fast(float x) {
    float xc = fminf(fmaxf(x, -15.f), 15.f);
    float t  = __builtin_amdgcn_exp2f(xc * 2.8853900817779268f); // e^(2x)
    return (t - 1.f) * __builtin_amdgcn_rcpf(t + 1.f);
}

// async 16B global->LDS (DMA; LDS side must be wave-uniform base + lane*16)
__device__ __forceinline__ void gl2lds16(const void* g, void* l) {
    __builtin_amdgcn_global_load_lds(
        (const __attribute__((address_space(1))) unsigned int*)g,
        (__attribute__((address_space(3))) unsigned int*)l, 16, 0, 0);
}

// XCD-locality swizzle: all 8 cb-siblings of a row-block get blockIdx%8 == rb%8
// -> same XCD (round-robin heuristic) -> A row-block L2-resident on re-read.
__device__ __forceinline__ void block_map(int bi, int& rb, int& cb) {
    int xcd  = bi & 7;
    int slot = bi >> 3;
    rb = xcd + 8 * (slot >> 3);
    cb = slot & 7;
}

// ---------- kernel 1: fused W_h->bf16 convert + bias = ln_b + W_vq@vq ----------
__global__ __launch_bounds__(256) void prep_kernel(const float* __restrict__ ln_w,
                                                   const float* __restrict__ ln_b,
                                                   const float* __restrict__ vq,
                                                   unsigned short* __restrict__ whb,
                                                   float* __restrict__ bias) {
    const int n = blockIdx.x;
    const int t = threadIdx.x;
    const int wave = t >> 6;
    const int lane = t & 63;
    // convert W_h row n (first 1024 cols)
    float4 v = ((const float4*)(ln_w + (size_t)n * 2048))[t];
    uint2 pk;
    pk.x = pack2bf(v.x, v.y);
    pk.y = pack2bf(v.z, v.w);
    *(uint2*)(whb + (size_t)n * 1024 + t * 4) = pk;
    // dot(W_vq row n, vq)
    const float* wrow = ln_w + (size_t)n * 2048 + 1024;
    float s = 0.f;
    #pragma unroll
    for (int j = 0; j < 4; ++j) {
        int k = t + j * 256;
        s += wrow[k] * vq[k];
    }
    #pragma unroll
    for (int off = 32; off; off >>= 1) s += __shfl_xor(s, off);
    __shared__ float red[4];
    if (lane == 0) red[wave] = s;
    __syncthreads();
    if (t == 0) bias[n] = ln_b[n] + red[0] + red[1] + red[2] + red[3];
}

// ---------- kernel 2: h -> bf16 ----------
__global__ __launch_bounds__(256) void convh_kernel(const float* __restrict__ h,
                                                    unsigned short* __restrict__ hb) {
    size_t idx = ((size_t)blockIdx.x * 256 + threadIdx.x) * 8;
    float4 a = *(const float4*)(h + idx);
    float4 b = *(const float4*)(h + idx + 4);
    uint4 p;
    p.x = pack2bf(a.x, a.y); p.y = pack2bf(a.z, a.w);
    p.z = pack2bf(b.x, b.y); p.w = pack2bf(b.z, b.w);
    *(uint4*)(hb + idx) = p;
}

// ---------- kernel 3a: bf16-A fused GEMM -> tanh -> dot v_w -> s (m97 structure) ----------
__global__ __launch_bounds__(256) void gemm_bf16_kernel(const unsigned short* __restrict__ hb,
                                                        const unsigned short* __restrict__ whb,
                                                        const float* __restrict__ bias,
                                                        const float* __restrict__ vw,
                                                        float* __restrict__ s_buf) {
    __shared__ __align__(16) unsigned short As[BM * BK]; // 8 KB
    __shared__ __align__(16) unsigned short Bs[BN * BK]; // 8 KB

    const int tid = threadIdx.x;
    int rb, cb;
    block_map(blockIdx.x, rb, cb);
    const int wave = tid >> 6;
    const int lane = tid & 63;
    const int quad = lane >> 4;
    const int l15  = lane & 15;
    const int wy   = wave >> 1;
    const int wx   = wave & 1;
    const int row0 = rb * BM;
    const int col0 = cb * BN;

    // DMA staging: LDS dest is lane-linear (tid*16 B); the XOR swizzle is applied
    // on the GLOBAL source address so LDS[row][slot] holds k-group (slot^swz(row)).
    const int srow = tid >> 2;           // 0..63 (issue 0); +64 for issue 1
    const int sg   = tid & 3;
    const int swz  = (srow >> 1) & 3;    // same for srow and srow+64
    const unsigned short* gA0 = hb  + (size_t)(row0 + srow) * 1024 + ((sg ^ swz) * 8);
    const unsigned short* gA1 = gA0 + (size_t)64 * 1024;
    const unsigned short* gB0 = whb + (size_t)(col0 + srow) * 1024 + ((sg ^ swz) * 8);
    const unsigned short* gB1 = gB0 + (size_t)64 * 1024;
    unsigned short* lA0 = As + tid * 8;          // byte tid*16
    unsigned short* lA1 = As + 2048 + tid * 8;   // byte 4096 + tid*16
    unsigned short* lB0 = Bs + tid * 8;
    unsigned short* lB1 = Bs + 2048 + tid * 8;

    // fragment read pointers (k-invariant; slot = quad ^ ((row>>1)&3))
    const unsigned short* rA[4];
    const unsigned short* rB[4];
    #pragma unroll
    for (int i = 0; i < 4; ++i) {
        int ra = wy * 64 + i * 16 + l15;
        rA[i] = As + ra * 32 + ((quad ^ ((ra >> 1) & 3)) * 8);
        int rn = wx * 64 + i * 16 + l15;
        rB[i] = Bs + rn * 32 + ((quad ^ ((rn >> 1) & 3)) * 8);
    }

    f32x4 acc[4][4];
    #pragma unroll
    for (int i = 0; i < 4; ++i)
        #pragma unroll
        for (int j = 0; j < 4; ++j)
            acc[i][j] = (f32x4){0.f, 0.f, 0.f, 0.f};

    for (int k0 = 0; k0 < 1024; k0 += BK) {
        __syncthreads();                 // prev iter's frag reads complete
        gl2lds16(gA0 + k0, lA0);
        gl2lds16(gA1 + k0, lA1);
        gl2lds16(gB0 + k0, lB0);
        gl2lds16(gB1 + k0, lB1);
        __syncthreads();                 // DMA drained (barrier waits vmcnt(0))

        bf16x8s af[4], bfv[4];
        #pragma unroll
        for (int i = 0; i < 4; ++i) af[i]  = *(const bf16x8s*)rA[i];
        #pragma unroll
        for (int i = 0; i < 4; ++i) bfv[i] = *(const bf16x8s*)rB[i];
        #pragma unroll
        for (int mt = 0; mt < 4; ++mt)
            #pragma unroll
            for (int nt = 0; nt < 4; ++nt)
                acc[mt][nt] = __builtin_amdgcn_mfma_f32_16x16x32_bf16(af[mt], bfv[nt], acc[mt][nt], 0, 0, 0);
    }

    // epilogue: s_partial[row] = sum_cols tanh(pre + bias) * v_w
    // C/D layout: col = lane&15, row = quad*4 + r   [m89/m91]
    const int colb = col0 + wx * 64 + l15;
    float vwv[4], bv[4];
    #pragma unroll
    for (int nt = 0; nt < 4; ++nt) {
        vwv[nt] = vw[colb + nt * 16];
        bv[nt]  = bias[colb + nt * 16];
    }
    const int rowb = row0 + wy * 64 + quad * 4;
    #pragma unroll
    for (int mt = 0; mt < 4; ++mt) {
        #pragma unroll
        for (int r = 0; r < 4; ++r) {
            float p = 0.f;
            #pragma unroll
            for (int nt = 0; nt < 4; ++nt)
                p += tanh_fast(acc[mt][nt][r] + bv[nt]) * vwv[nt];
            p += __shfl_xor(p, 1);
            p += __shfl_xor(p, 2);
            p += __shfl_xor(p, 4);
            p += __shfl_xor(p, 8);
            if (l15 == 0) atomicAdd(&s_buf[rowb + mt * 16 + r], p);
        }
    }
}

// ---------- kernel 3b: fp32-A fallback (inline bf16 pack), ws too small ----------
__global__ __launch_bounds__(256) void gemm_tanh_kernel(const float* __restrict__ hmat,
                                                        const unsigned short* __restrict__ whb,
                                                        const float* __restrict__ bias,
                                                        const float* __restrict__ vw,
                                                        float* __restrict__ s_buf) {
    __shared__ __align__(16) unsigned short As[BM * BK];
    __shared__ __align__(16) unsigned short Bs[BN * BK];

    const int tid = threadIdx.x;
    int rb, cb;
    block_map(blockIdx.x, rb, cb);
    const int wave = tid >> 6;
    const int lane = tid & 63;
    const int quad = lane >> 4;
    const int l15  = lane & 15;
    const int wy   = wave >> 1;
    const int wx   = wave & 1;
    const int row0 = rb * BM;
    const int col0 = cb * BN;

    const int srow = tid >> 2;
    const int sg   = tid & 3;
    const int swz  = (srow >> 1) & 3;
    const float*          gA0 = hmat + (size_t)(row0 + srow)      * 1024 + sg * 8;
    const float*          gA1 = hmat + (size_t)(row0 + srow + 64) * 1024 + sg * 8;
    const unsigned short* gB0 = whb  + (size_t)(col0 + srow)      * 1024 + ((sg ^ swz) * 8);
    const unsigned short* gB1 = gB0 + (size_t)64 * 1024;
    unsigned short* wA0 = As + srow * 32 + ((sg ^ swz) * 8);
    unsigned short* wA1 = wA0 + 64 * 32;
    unsigned short* lB0 = Bs + tid * 8;
    unsigned short* lB1 = Bs + 2048 + tid * 8;

    const unsigned short* rA[4];
    const unsigned short* rB[4];
    #pragma unroll
    for (int i = 0; i < 4; ++i) {
        int ra = wy * 64 + i * 16 + l15;
        rA[i] = As + ra * 32 + ((quad ^ ((ra >> 1) & 3)) * 8);
        int rn = wx * 64 + i * 16 + l15;
        rB[i] = Bs + rn * 32 + ((quad ^ ((rn >> 1) & 3)) * 8);
    }

    f32x4 acc[4][4];
    #pragma unroll
    for (int i = 0; i < 4; ++i)
        #pragma unroll
        for (int j = 0; j < 4; ++j)
            acc[i][j] = (f32x4){0.f, 0.f, 0.f, 0.f};

    for (int k0 = 0; k0 < 1024; k0 += BK) {
        float4 va0 = *(const float4*)(gA0 + k0);
        float4 va1 = *(const float4*)(gA0 + k0 + 4);
        float4 va2 = *(const float4*)(gA1 + k0);
        float4 va3 = *(const float4*)(gA1 + k0 + 4);

        __syncthreads();
        gl2lds16(gB0 + k0, lB0);
        gl2lds16(gB1 + k0, lB1);

        uint4 pa0, pa1;
        pa0.x = pack2bf(va0.x, va0.y); pa0.y = pack2bf(va0.z, va0.w);
        pa0.z = pack2bf(va1.x, va1.y); pa0.w = pack2bf(va1.z, va1.w);
        pa1.x = pack2bf(va2.x, va2.y); pa1.y = pack2bf(va2.z, va2.w);
        pa1.z = pack2bf(va3.x, va3.y); pa1.w = pack2bf(va3.z, va3.w);
        *(uint4*)wA0 = pa0;
        *(uint4*)wA1 = pa1;

        __syncthreads();

        bf16x8s af[4], bfv[4];
        #pragma unroll
        for (int i = 0; i < 4; ++i) af[i]  = *(const bf16x8s*)rA[i];
        #pragma unroll
        for (int i = 0; i < 4; ++i) bfv[i] = *(const bf16x8s*)rB[i];
        #pragma unroll
        for (int mt = 0; mt < 4; ++mt)
            #pragma unroll
            for (int nt = 0; nt < 4; ++nt)
                acc[mt][nt] = __builtin_amdgcn_mfma_f32_16x16x32_bf16(af[mt], bfv[nt], acc[mt][nt], 0, 0, 0);
    }

    const int colb = col0 + wx * 64 + l15;
    float vwv[4], bv[4];
    #pragma unroll
    for (int nt = 0; nt < 4; ++nt) {
        vwv[nt] = vw[colb + nt * 16];
        bv[nt]  = bias[colb + nt * 16];
    }
    const int rowb = row0 + wy * 64 + quad * 4;
    #pragma unroll
    for (int mt = 0; mt < 4; ++mt) {
        #pragma unroll
        for (int r = 0; r < 4; ++r) {
            float p = 0.f;
            #pragma unroll
            for (int nt = 0; nt < 4; ++nt)
                p += tanh_fast(acc[mt][nt][r] + bv[nt]) * vwv[nt];
            p += __shfl_xor(p, 1);
            p += __shfl_xor(p, 2);
            p += __shfl_xor(p, 4);
            p += __shfl_xor(p, 8);
            if (l15 == 0) atomicAdd(&s_buf[rowb + mt * 16 + r], p);
        }
    }
}

// ---------- kernel 4: masked softmax over L per batch ----------
__global__ __launch_bounds__(256) void softmax_kernel(const float* __restrict__ s_buf,
                                                      const int* __restrict__ mask,
                                                      float* __restrict__ a_buf) {
    const int b    = blockIdx.x;
    const int t    = threadIdx.x;
    const int wave = t >> 6;
    const int lane = t & 63;
    __shared__ float redm[4];
    __shared__ float reds[4];
    float sv[8];
    float mx = -3.0e38f;
    #pragma unroll
    for (int j = 0; j < 8; ++j) {
        int l = t + j * 256;
        float v = s_buf[b * 2048 + l];
        if (mask[b * 2048 + l] == 0) v -= 10000.f;
        sv[j] = v;
        mx = fmaxf(mx, v);
    }
    #pragma unroll
    for (int off = 32; off; off >>= 1) mx = fmaxf(mx, __shfl_xor(mx, off));
    if (lane == 0) redm[wave] = mx;
    __syncthreads();
    mx = fmaxf(fmaxf(redm[0], redm[1]), fmaxf(redm[2], redm[3]));
    float sum = 0.f;
    #pragma unroll
    for (int j = 0; j < 8; ++j) {
        sv[j] = __expf(sv[j] - mx);
        sum += sv[j];
    }
    #pragma unroll
    for (int off = 32; off; off >>= 1) sum += __shfl_xor(sum, off);
    if (lane == 0) reds[wave] = sum;
    __syncthreads();
    sum = reds[0] + reds[1] + reds[2] + reds[3];
    float inv = 1.f / sum;
    #pragma unroll
    for (int j = 0; j < 8; ++j)
        a_buf[b * 2048 + t + j * 256] = sv[j] * inv;
}

// ---------- kernel 5: r[b,i] = sum_l a[b,l] * h[b,l,i] (fp32 h for accuracy) ----------
__global__ __launch_bounds__(256) void r_kernel(const float* __restrict__ hmat,
                                                const float* __restrict__ a_buf,
                                                float* __restrict__ out) {
    const int b  = blockIdx.x >> 5;
    const int lc = blockIdx.x & 31;
    const int t  = threadIdx.x;
    __shared__ float aw[64];
    if (t < 64) aw[t] = a_buf[b * 2048 + lc * 64 + t];
    __syncthreads();
    const float4* hp = (const float4*)hmat + (size_t)(b * 2048 + lc * 64) * 256;
    float ax = 0.f, ay = 0.f, az = 0.f, aq = 0.f;
    #pragma unroll 8
    for (int l = 0; l < 64; ++l) {
        float4 hv = hp[(size_t)l * 256 + t];
        float av = aw[l];
        ax += av * hv.x; ay += av * hv.y; az += av * hv.z; aq += av * hv.w;
    }
    float* op = out + b * 1024 + t * 4;
    atomicAdd(op + 0, ax);
    atomicAdd(op + 1, ay);
    atomicAdd(op + 2, az);
    atomicAdd(op + 3, aq);
}

// ---------- launch ----------
extern "C" void kernel_launch(void* const* d_in, const int* in_sizes, int n_in,
                              void* d_out, int out_size, void* d_ws, size_t ws_size,
                              hipStream_t stream) {
    const float* h    = (const float*)d_in[0];
    const int*   mask = (const int*)d_in[1];
    const float* ln_w = (const float*)d_in[2];
    const float* ln_b = (const float*)d_in[3];
    const float* v_w  = (const float*)d_in[4];
    const float* vq   = (const float*)d_in[5];
    float* out = (float*)d_out;

    char* ws = (char*)d_ws;
    unsigned short* whb = (unsigned short*)(ws + WHB_OFF);
    float* bias         = (float*)(ws + BIAS_OFF);
    float* s_buf        = (float*)(ws + SBUF_OFF);
    float* a_buf        = (float*)(ws + ABUF_OFF);
    unsigned short* hb  = (unsigned short*)(ws + HB_OFF);

    const bool use_bf16_h = (ws_size >= WS_NEED_BF16);

    hipMemsetAsync(s_buf, 0, NROWS * sizeof(float), stream);
    hipMemsetAsync(d_out, 0, (size_t)out_size * sizeof(float), stream);

    prep_kernel<<<1024, 256, 0, stream>>>(ln_w, ln_b, vq, whb, bias);
    if (use_bf16_h) {
        convh_kernel<<<32768, 256, 0, stream>>>(h, hb);
        gemm_bf16_kernel<<<(NROWS / BM) * (HID / BN), 256, 0, stream>>>(hb, whb, bias, v_w, s_buf);
    } else {
        gemm_tanh_kernel<<<(NROWS / BM) * (HID / BN), 256, 0, stream>>>(h, whb, bias, v_w, s_buf);
    }
    softmax_kernel<<<BATCH, 256, 0, stream>>>(s_buf, mask, a_buf);
    r_kernel<<<BATCH * 32, 256, 0, stream>>>(h, a_buf, out);
}

// Round 3
// 601.266 us; speedup vs baseline: 1.0528x; 1.0121x over previous
//
#include <hip/hip_runtime.h>
#include <hip/hip_bf16.h>

// ---------- types ----------
typedef short  bf16x8s __attribute__((ext_vector_type(8)));  // 8 bf16 (4 VGPRs)
typedef float  f32x4   __attribute__((ext_vector_type(4)));  // 4 fp32 acc

#define BATCH 32
#define SEQL  2048
#define NROWS (BATCH * SEQL)   // 65536
#define IN    1024
#define HID   1024

#define BM 128
#define BN 128

// workspace layout
#define WHB_OFF   0u          // 2 MB   bf16 W_h
#define BIAS_OFF  0x200000u   // 4 KB
#define SPART_OFF 0x210000u   // 4 MB   s partials [16][65536]
#define ABUF_OFF  0x610000u   // 256 KB softmax weights
#define HB_OFF    0x650000u   // 128 MB bf16 h
#define WS_NEED_BF16 ((size_t)HB_OFF + (size_t)NROWS * IN * 2)

// pack two fp32 -> two bf16 (round-up-on-half via +0x8000, v_perm byte select)
__device__ __forceinline__ unsigned int pack2bf(float f0, float f1) {
    unsigned int u0 = __float_as_uint(f0) + 0x8000u;
    unsigned int u1 = __float_as_uint(f1) + 0x8000u;
    return __builtin_amdgcn_perm(u1, u0, 0x07060302u);
}

__device__ __forceinline__ float tanh_fast(float x) {
    float xc = fminf(fmaxf(x, -15.f), 15.f);
    float t  = __builtin_amdgcn_exp2f(xc * 2.8853900817779268f); // e^(2x)
    return (t - 1.f) * __builtin_amdgcn_rcpf(t + 1.f);
}

// async 16B global->LDS (DMA; LDS dest = wave-uniform base + lane*16)
__device__ __forceinline__ void gl2lds16(const void* g, void* l) {
    __builtin_amdgcn_global_load_lds(
        (const __attribute__((address_space(1))) unsigned int*)g,
        (__attribute__((address_space(3))) unsigned int*)l, 16, 0, 0);
}

// XCD-locality swizzle: all 8 cb-siblings of a row-block share blockIdx%8
// -> same XCD (round-robin) -> A row-block stays L2-resident across re-reads.
// [R2 measured: FETCH 1.06GB -> 92MB]
__device__ __forceinline__ void block_map(int bi, int& rb, int& cb) {
    int xcd  = bi & 7;
    int slot = bi >> 3;
    rb = xcd + 8 * (slot >> 3);
    cb = slot & 7;
}

// ---------- kernel 1: fused [W_h->bf16 + bias] (blocks 0..1023) and h->bf16 (rest) ----
__global__ __launch_bounds__(256) void prep_kernel(const float* __restrict__ ln_w,
                                                   const float* __restrict__ ln_b,
                                                   const float* __restrict__ vq,
                                                   const float* __restrict__ h,
                                                   unsigned short* __restrict__ whb,
                                                   float* __restrict__ bias,
                                                   unsigned short* __restrict__ hb) {
    const int bi = blockIdx.x;
    const int t  = threadIdx.x;
    if (bi < 1024) {
        const int n = bi;
        const int wave = t >> 6;
        const int lane = t & 63;
        float4 v = ((const float4*)(ln_w + (size_t)n * 2048))[t];
        uint2 pk;
        pk.x = pack2bf(v.x, v.y);
        pk.y = pack2bf(v.z, v.w);
        *(uint2*)(whb + (size_t)n * 1024 + t * 4) = pk;
        const float* wrow = ln_w + (size_t)n * 2048 + 1024;
        float s = 0.f;
        #pragma unroll
        for (int j = 0; j < 4; ++j) {
            int k = t + j * 256;
            s += wrow[k] * vq[k];
        }
        #pragma unroll
        for (int off = 32; off; off >>= 1) s += __shfl_xor(s, off);
        __shared__ float red[4];
        if (lane == 0) red[wave] = s;
        __syncthreads();
        if (t == 0) bias[n] = ln_b[n] + red[0] + red[1] + red[2] + red[3];
    } else {
        size_t idx = ((size_t)(bi - 1024) * 256 + t) * 8;
        float4 a = *(const float4*)(h + idx);
        float4 b = *(const float4*)(h + idx + 4);
        uint4 p;
        p.x = pack2bf(a.x, a.y); p.y = pack2bf(a.z, a.w);
        p.z = pack2bf(b.x, b.y); p.w = pack2bf(b.z, b.w);
        *(uint4*)(hb + idx) = p;
    }
}

// ---------- kernel 2: bf16 GEMM, BK=64 (two proven 8KB sub-tiles/operand) ----------
// epilogue: s_part[cb*2+wx][row] = partial of sum_cols tanh(pre+bias)*v_w (plain store)
__global__ __launch_bounds__(256) void gemm64_kernel(const unsigned short* __restrict__ hb,
                                                     const unsigned short* __restrict__ whb,
                                                     const float* __restrict__ bias,
                                                     const float* __restrict__ vw,
                                                     float* __restrict__ s_part) {
    __shared__ __align__(16) unsigned short As[8192]; // 16 KB: sub-tile s at s*4096 shorts
    __shared__ __align__(16) unsigned short Bs[8192]; // 16 KB

    const int tid = threadIdx.x;
    int rb, cb;
    block_map(blockIdx.x, rb, cb);
    const int wave = tid >> 6;
    const int lane = tid & 63;
    const int quad = lane >> 4;
    const int l15  = lane & 15;
    const int wy   = wave >> 1;
    const int wx   = wave & 1;
    const int row0 = rb * BM;
    const int col0 = cb * BN;

    // DMA staging (per 8KB sub-tile, proven R2 layout: row stride 32 shorts,
    // slot sg holds k-group sg^swz(row), swz=(row>>1)&3)
    const int srow = tid >> 2;
    const int sg   = tid & 3;
    const int swz  = (srow >> 1) & 3;
    const unsigned short* gA = hb  + (size_t)(row0 + srow) * 1024 + ((sg ^ swz) * 8);
    const unsigned short* gB = whb + (size_t)(col0 + srow) * 1024 + ((sg ^ swz) * 8);
    unsigned short* lA = As + tid * 8;
    unsigned short* lB = Bs + tid * 8;

    // fragment read pointers, sub-tile 0 (sub 1 = +4096 shorts)
    const unsigned short* rA[4];
    const unsigned short* rB[4];
    #pragma unroll
    for (int i = 0; i < 4; ++i) {
        int ra = wy * 64 + i * 16 + l15;
        rA[i] = As + ra * 32 + ((quad ^ ((ra >> 1) & 3)) * 8);
        int rn = wx * 64 + i * 16 + l15;
        rB[i] = Bs + rn * 32 + ((quad ^ ((rn >> 1) & 3)) * 8);
    }

    f32x4 acc[4][4];
    #pragma unroll
    for (int i = 0; i < 4; ++i)
        #pragma unroll
        for (int j = 0; j < 4; ++j)
            acc[i][j] = (f32x4){0.f, 0.f, 0.f, 0.f};

    for (int k0 = 0; k0 < 1024; k0 += 64) {
        __syncthreads();                 // prev iter's frag reads complete
        // sub-tile 0 (k0..k0+31)
        gl2lds16(gA + k0,          lA);
        gl2lds16(gA + 65536 + k0,  lA + 2048);
        gl2lds16(gB + k0,          lB);
        gl2lds16(gB + 65536 + k0,  lB + 2048);
        // sub-tile 1 (k0+32..k0+63)
        gl2lds16(gA + k0 + 32,         lA + 4096);
        gl2lds16(gA + 65536 + k0 + 32, lA + 6144);
        gl2lds16(gB + k0 + 32,         lB + 4096);
        gl2lds16(gB + 65536 + k0 + 32, lB + 6144);
        __syncthreads();                 // DMA drained

        bf16x8s af0[4], bf0[4], af1[4], bf1[4];
        #pragma unroll
        for (int i = 0; i < 4; ++i) af0[i] = *(const bf16x8s*)rA[i];
        #pragma unroll
        for (int i = 0; i < 4; ++i) bf0[i] = *(const bf16x8s*)rB[i];
        #pragma unroll
        for (int mt = 0; mt < 4; ++mt)
            #pragma unroll
            for (int nt = 0; nt < 4; ++nt)
                acc[mt][nt] = __builtin_amdgcn_mfma_f32_16x16x32_bf16(af0[mt], bf0[nt], acc[mt][nt], 0, 0, 0);
        #pragma unroll
        for (int i = 0; i < 4; ++i) af1[i] = *(const bf16x8s*)(rA[i] + 4096);
        #pragma unroll
        for (int i = 0; i < 4; ++i) bf1[i] = *(const bf16x8s*)(rB[i] + 4096);
        #pragma unroll
        for (int mt = 0; mt < 4; ++mt)
            #pragma unroll
            for (int nt = 0; nt < 4; ++nt)
                acc[mt][nt] = __builtin_amdgcn_mfma_f32_16x16x32_bf16(af1[mt], bf1[nt], acc[mt][nt], 0, 0, 0);
    }

    // epilogue: C/D layout col=lane&15, row=quad*4+r [m89/m91]
    const int colb = col0 + wx * 64 + l15;
    float vwv[4], bv[4];
    #pragma unroll
    for (int nt = 0; nt < 4; ++nt) {
        vwv[nt] = vw[colb + nt * 16];
        bv[nt]  = bias[colb + nt * 16];
    }
    const int rowb = row0 + wy * 64 + quad * 4;
    float* sp = s_part + (size_t)(cb * 2 + wx) * NROWS;
    #pragma unroll
    for (int mt = 0; mt < 4; ++mt) {
        #pragma unroll
        for (int r = 0; r < 4; ++r) {
            float p = 0.f;
            #pragma unroll
            for (int nt = 0; nt < 4; ++nt)
                p += tanh_fast(acc[mt][nt][r] + bv[nt]) * vwv[nt];
            p += __shfl_xor(p, 1);
            p += __shfl_xor(p, 2);
            p += __shfl_xor(p, 4);
            p += __shfl_xor(p, 8);
            if (l15 == 0) sp[rowb + mt * 16 + r] = p;
        }
    }
}

// ---------- kernel 2b: fp32-A fallback (inline pack), only if ws too small ----------
__global__ __launch_bounds__(256) void gemm_f32_kernel(const float* __restrict__ hmat,
                                                       const unsigned short* __restrict__ whb,
                                                       const float* __restrict__ bias,
                                                       const float* __restrict__ vw,
                                                       float* __restrict__ s_part) {
    __shared__ __align__(16) unsigned short As[4096];
    __shared__ __align__(16) unsigned short Bs[4096];
    const int tid = threadIdx.x;
    int rb, cb;
    block_map(blockIdx.x, rb, cb);
    const int wave = tid >> 6;
    const int lane = tid & 63;
    const int quad = lane >> 4;
    const int l15  = lane & 15;
    const int wy   = wave >> 1;
    const int wx   = wave & 1;
    const int row0 = rb * BM;
    const int col0 = cb * BN;
    const int srow = tid >> 2;
    const int sg   = tid & 3;
    const int swz  = (srow >> 1) & 3;
    const float*          gA0 = hmat + (size_t)(row0 + srow)      * 1024 + sg * 8;
    const float*          gA1 = hmat + (size_t)(row0 + srow + 64) * 1024 + sg * 8;
    const unsigned short* gB0 = whb  + (size_t)(col0 + srow)      * 1024 + ((sg ^ swz) * 8);
    unsigned short* wA0 = As + srow * 32 + ((sg ^ swz) * 8);
    unsigned short* wA1 = wA0 + 64 * 32;
    unsigned short* lB0 = Bs + tid * 8;
    const unsigned short* rA[4];
    const unsigned short* rB[4];
    #pragma unroll
    for (int i = 0; i < 4; ++i) {
        int ra = wy * 64 + i * 16 + l15;
        rA[i] = As + ra * 32 + ((quad ^ ((ra >> 1) & 3)) * 8);
        int rn = wx * 64 + i * 16 + l15;
        rB[i] = Bs + rn * 32 + ((quad ^ ((rn >> 1) & 3)) * 8);
    }
    f32x4 acc[4][4];
    #pragma unroll
    for (int i = 0; i < 4; ++i)
        #pragma unroll
        for (int j = 0; j < 4; ++j)
            acc[i][j] = (f32x4){0.f, 0.f, 0.f, 0.f};
    for (int k0 = 0; k0 < 1024; k0 += 32) {
        float4 va0 = *(const float4*)(gA0 + k0);
        float4 va1 = *(const float4*)(gA0 + k0 + 4);
        float4 va2 = *(const float4*)(gA1 + k0);
        float4 va3 = *(const float4*)(gA1 + k0 + 4);
        __syncthreads();
        gl2lds16(gB0 + k0, lB0);
        gl2lds16(gB0 + 65536 + k0, lB0 + 2048);
        uint4 pa0, pa1;
        pa0.x = pack2bf(va0.x, va0.y); pa0.y = pack2bf(va0.z, va0.w);
        pa0.z = pack2bf(va1.x, va1.y); pa0.w = pack2bf(va1.z, va1.w);
        pa1.x = pack2bf(va2.x, va2.y); pa1.y = pack2bf(va2.z, va2.w);
        pa1.z = pack2bf(va3.x, va3.y); pa1.w = pack2bf(va3.z, va3.w);
        *(uint4*)wA0 = pa0;
        *(uint4*)wA1 = pa1;
        __syncthreads();
        bf16x8s af[4], bfv[4];
        #pragma unroll
        for (int i = 0; i < 4; ++i) af[i]  = *(const bf16x8s*)rA[i];
        #pragma unroll
        for (int i = 0; i < 4; ++i) bfv[i] = *(const bf16x8s*)rB[i];
        #pragma unroll
        for (int mt = 0; mt < 4; ++mt)
            #pragma unroll
            for (int nt = 0; nt < 4; ++nt)
                acc[mt][nt] = __builtin_amdgcn_mfma_f32_16x16x32_bf16(af[mt], bfv[nt], acc[mt][nt], 0, 0, 0);
    }
    const int colb = col0 + wx * 64 + l15;
    float vwv[4], bv[4];
    #pragma unroll
    for (int nt = 0; nt < 4; ++nt) {
        vwv[nt] = vw[colb + nt * 16];
        bv[nt]  = bias[colb + nt * 16];
    }
    const int rowb = row0 + wy * 64 + quad * 4;
    float* sp = s_part + (size_t)(cb * 2 + wx) * NROWS;
    #pragma unroll
    for (int mt = 0; mt < 4; ++mt) {
        #pragma unroll
        for (int r = 0; r < 4; ++r) {
            float p = 0.f;
            #pragma unroll
            for (int nt = 0; nt < 4; ++nt)
                p += tanh_fast(acc[mt][nt][r] + bv[nt]) * vwv[nt];
            p += __shfl_xor(p, 1);
            p += __shfl_xor(p, 2);
            p += __shfl_xor(p, 4);
            p += __shfl_xor(p, 8);
            if (l15 == 0) sp[rowb + mt * 16 + r] = p;
        }
    }
}

// ---------- kernel 3: sum partials + masked softmax; also zeroes d_out ----------
__global__ __launch_bounds__(256) void softmax_kernel(const float* __restrict__ s_part,
                                                      const int* __restrict__ mask,
                                                      float* __restrict__ a_buf,
                                                      float* __restrict__ out) {
    const int b    = blockIdx.x;
    const int t    = threadIdx.x;
    const int wave = t >> 6;
    const int lane = t & 63;
    // zero the output slice this batch will atomically accumulate into (kernel 4)
    ((float4*)(out + b * 1024))[t] = (float4){0.f, 0.f, 0.f, 0.f};
    __shared__ float redm[4];
    __shared__ float reds[4];
    float sv[8];
    float mx = -3.0e38f;
    #pragma unroll
    for (int j = 0; j < 8; ++j) {
        int l = t + j * 256;
        float v = 0.f;
        #pragma unroll
        for (int c = 0; c < 16; ++c)
            v += s_part[(size_t)c * NROWS + b * 2048 + l];
        if (mask[b * 2048 + l] == 0) v -= 10000.f;
        sv[j] = v;
        mx = fmaxf(mx, v);
    }
    #pragma unroll
    for (int off = 32; off; off >>= 1) mx = fmaxf(mx, __shfl_xor(mx, off));
    if (lane == 0) redm[wave] = mx;
    __syncthreads();
    mx = fmaxf(fmaxf(redm[0], redm[1]), fmaxf(redm[2], redm[3]));
    float sum = 0.f;
    #pragma unroll
    for (int j = 0; j < 8; ++j) {
        sv[j] = __expf(sv[j] - mx);
        sum += sv[j];
    }
    #pragma unroll
    for (int off = 32; off; off >>= 1) sum += __shfl_xor(sum, off);
    if (lane == 0) reds[wave] = sum;
    __syncthreads();
    sum = reds[0] + reds[1] + reds[2] + reds[3];
    float inv = 1.f / sum;
    #pragma unroll
    for (int j = 0; j < 8; ++j)
        a_buf[b * 2048 + t + j * 256] = sv[j] * inv;
}

// ---------- kernel 4a: r[b,i] = sum_l a[b,l]*h[b,l,i], bf16 h (halved read) ----------
__global__ __launch_bounds__(256) void r_bf16_kernel(const unsigned short* __restrict__ hb,
                                                     const float* __restrict__ a_buf,
                                                     float* __restrict__ out) {
    const int b  = blockIdx.x >> 5;
    const int lc = blockIdx.x & 31;
    const int t  = threadIdx.x;
    __shared__ float aw[64];
    if (t < 64) aw[t] = a_buf[b * 2048 + lc * 64 + t];
    __syncthreads();
    const uint2* hp = (const uint2*)(hb + (size_t)(b * 2048 + lc * 64) * 1024) + t;
    float a0 = 0.f, a1 = 0.f, a2 = 0.f, a3 = 0.f;
    #pragma unroll 8
    for (int l = 0; l < 64; ++l) {
        uint2 v = hp[(size_t)l * 256];
        float av = aw[l];
        a0 += av * __uint_as_float(v.x << 16);
        a1 += av * __uint_as_float(v.x & 0xffff0000u);
        a2 += av * __uint_as_float(v.y << 16);
        a3 += av * __uint_as_float(v.y & 0xffff0000u);
    }
    float* op = out + b * 1024 + t * 4;
    atomicAdd(op + 0, a0);
    atomicAdd(op + 1, a1);
    atomicAdd(op + 2, a2);
    atomicAdd(op + 3, a3);
}

// ---------- kernel 4b: fp32 fallback ----------
__global__ __launch_bounds__(256) void r_f32_kernel(const float* __restrict__ hmat,
                                                    const float* __restrict__ a_buf,
                                                    float* __restrict__ out) {
    const int b  = blockIdx.x >> 5;
    const int lc = blockIdx.x & 31;
    const int t  = threadIdx.x;
    __shared__ float aw[64];
    if (t < 64) aw[t] = a_buf[b * 2048 + lc * 64 + t];
    __syncthreads();
    const float4* hp = (const float4*)hmat + (size_t)(b * 2048 + lc * 64) * 256;
    float ax = 0.f, ay = 0.f, az = 0.f, aq = 0.f;
    #pragma unroll 8
    for (int l = 0; l < 64; ++l) {
        float4 hv = hp[(size_t)l * 256 + t];
        float av = aw[l];
        ax += av * hv.x; ay += av * hv.y; az += av * hv.z; aq += av * hv.w;
    }
    float* op = out + b * 1024 + t * 4;
    atomicAdd(op + 0, ax);
    atomicAdd(op + 1, ay);
    atomicAdd(op + 2, az);
    atomicAdd(op + 3, aq);
}

// ---------- launch (4 dispatches, no memsets) ----------
extern "C" void kernel_launch(void* const* d_in, const int* in_sizes, int n_in,
                              void* d_out, int out_size, void* d_ws, size_t ws_size,
                              hipStream_t stream) {
    const float* h    = (const float*)d_in[0];
    const int*   mask = (const int*)d_in[1];
    const float* ln_w = (const float*)d_in[2];
    const float* ln_b = (const float*)d_in[3];
    const float* v_w  = (const float*)d_in[4];
    const float* vq   = (const float*)d_in[5];
    float* out = (float*)d_out;

    char* ws = (char*)d_ws;
    unsigned short* whb = (unsigned short*)(ws + WHB_OFF);
    float* bias         = (float*)(ws + BIAS_OFF);
    float* s_part       = (float*)(ws + SPART_OFF);
    float* a_buf        = (float*)(ws + ABUF_OFF);
    unsigned short* hb  = (unsigned short*)(ws + HB_OFF);

    const bool use_bf16_h = (ws_size >= WS_NEED_BF16);

    if (use_bf16_h) {
        prep_kernel<<<1024 + 32768, 256, 0, stream>>>(ln_w, ln_b, vq, h, whb, bias, hb);
        gemm64_kernel<<<(NROWS / BM) * (HID / BN), 256, 0, stream>>>(hb, whb, bias, v_w, s_part);
        softmax_kernel<<<BATCH, 256, 0, stream>>>(s_part, mask, a_buf, out);
        r_bf16_kernel<<<BATCH * 32, 256, 0, stream>>>(hb, a_buf, out);
    } else {
        prep_kernel<<<1024, 256, 0, stream>>>(ln_w, ln_b, vq, h, whb, bias, hb);
        gemm_f32_kernel<<<(NROWS / BM) * (HID / BN), 256, 0, stream>>>(h, whb, bias, v_w, s_part);
        softmax_kernel<<<BATCH, 256, 0, stream>>>(s_part, mask, a_buf, out);
        r_f32_kernel<<<BATCH * 32, 256, 0, stream>>>(h, a_buf, out);
    }
}

// Round 4
// 580.608 us; speedup vs baseline: 1.0903x; 1.0356x over previous
//
#include <hip/hip_runtime.h>
#include <hip/hip_bf16.h>

// ---------- types ----------
typedef short  bf16x8s __attribute__((ext_vector_type(8)));  // 8 bf16 (4 VGPRs)
typedef float  f32x4   __attribute__((ext_vector_type(4)));  // 4 fp32 acc

#define BATCH 32
#define SEQL  2048
#define NROWS (BATCH * SEQL)   // 65536
#define IN    1024
#define HID   1024

#define BM 128
#define BN 128

// workspace layout
#define WHB_OFF   0u          // 2 MB   bf16 W_h
#define BIAS_OFF  0x200000u   // 4 KB
#define SPART_OFF 0x210000u   // 4 MB   s partials [16][65536]
#define ABUF_OFF  0x610000u   // 256 KB softmax weights
#define HB_OFF    0x650000u   // 128 MB bf16 h
#define WS_NEED_BF16 ((size_t)HB_OFF + (size_t)NROWS * IN * 2)

// pack two fp32 -> two bf16 (round-up-on-half via +0x8000, v_perm byte select)
__device__ __forceinline__ unsigned int pack2bf(float f0, float f1) {
    unsigned int u0 = __float_as_uint(f0) + 0x8000u;
    unsigned int u1 = __float_as_uint(f1) + 0x8000u;
    return __builtin_amdgcn_perm(u1, u0, 0x07060302u);
}

__device__ __forceinline__ float tanh_fast(float x) {
    float xc = fminf(fmaxf(x, -15.f), 15.f);
    float t  = __builtin_amdgcn_exp2f(xc * 2.8853900817779268f); // e^(2x)
    return (t - 1.f) * __builtin_amdgcn_rcpf(t + 1.f);
}

// async 16B global->LDS (DMA; LDS dest = wave-uniform base + lane*16)
__device__ __forceinline__ void gl2lds16(const void* g, void* l) {
    __builtin_amdgcn_global_load_lds(
        (const __attribute__((address_space(1))) unsigned int*)g,
        (__attribute__((address_space(3))) unsigned int*)l, 16, 0, 0);
}

// XCD-locality swizzle: all 8 cb-siblings of a row-block share blockIdx%8
// -> same XCD (round-robin) -> A row-block stays L2-resident across re-reads.
// [R2 measured: FETCH 1.06GB -> 92MB]
__device__ __forceinline__ void block_map(int bi, int& rb, int& cb) {
    int xcd  = bi & 7;
    int slot = bi >> 3;
    rb = xcd + 8 * (slot >> 3);
    cb = slot & 7;
}

// ---------- kernel 1: fused [W_h->bf16 + bias] (blocks 0..1023) and h->bf16 (rest) ----
__global__ __launch_bounds__(256) void prep_kernel(const float* __restrict__ ln_w,
                                                   const float* __restrict__ ln_b,
                                                   const float* __restrict__ vq,
                                                   const float* __restrict__ h,
                                                   unsigned short* __restrict__ whb,
                                                   float* __restrict__ bias,
                                                   unsigned short* __restrict__ hb) {
    const int bi = blockIdx.x;
    const int t  = threadIdx.x;
    if (bi < 1024) {
        const int n = bi;
        const int wave = t >> 6;
        const int lane = t & 63;
        float4 v = ((const float4*)(ln_w + (size_t)n * 2048))[t];
        uint2 pk;
        pk.x = pack2bf(v.x, v.y);
        pk.y = pack2bf(v.z, v.w);
        *(uint2*)(whb + (size_t)n * 1024 + t * 4) = pk;
        const float* wrow = ln_w + (size_t)n * 2048 + 1024;
        float s = 0.f;
        #pragma unroll
        for (int j = 0; j < 4; ++j) {
            int k = t + j * 256;
            s += wrow[k] * vq[k];
        }
        #pragma unroll
        for (int off = 32; off; off >>= 1) s += __shfl_xor(s, off);
        __shared__ float red[4];
        if (lane == 0) red[wave] = s;
        __syncthreads();
        if (t == 0) bias[n] = ln_b[n] + red[0] + red[1] + red[2] + red[3];
    } else {
        size_t idx = ((size_t)(bi - 1024) * 256 + t) * 8;
        float4 a = *(const float4*)(h + idx);
        float4 b = *(const float4*)(h + idx + 4);
        uint4 p;
        p.x = pack2bf(a.x, a.y); p.y = pack2bf(a.z, a.w);
        p.z = pack2bf(b.x, b.y); p.w = pack2bf(b.z, b.w);
        *(uint4*)(hb + idx) = p;
    }
}

// ---------- kernel 2: bf16 GEMM, BK=32 single-buffer (R2-proven: 199us) ----------
// epilogue: s_part[cb*2+wx][row] = partial of sum_cols tanh(pre+bias)*v_w (plain store)
__global__ __launch_bounds__(256) void gemm32_kernel(const unsigned short* __restrict__ hb,
                                                     const unsigned short* __restrict__ whb,
                                                     const float* __restrict__ bias,
                                                     const float* __restrict__ vw,
                                                     float* __restrict__ s_part) {
    __shared__ __align__(16) unsigned short As[4096]; // 8 KB
    __shared__ __align__(16) unsigned short Bs[4096]; // 8 KB

    const int tid = threadIdx.x;
    int rb, cb;
    block_map(blockIdx.x, rb, cb);
    const int wave = tid >> 6;
    const int lane = tid & 63;
    const int quad = lane >> 4;
    const int l15  = lane & 15;
    const int wy   = wave >> 1;
    const int wx   = wave & 1;
    const int row0 = rb * BM;
    const int col0 = cb * BN;

    // DMA staging (R2-proven layout: row stride 32 shorts; slot sg holds
    // k-group sg^swz(row), swz=(row>>1)&3; LDS dest lane-linear tid*16B)
    const int srow = tid >> 2;
    const int sg   = tid & 3;
    const int swz  = (srow >> 1) & 3;
    const unsigned short* gA0 = hb  + (size_t)(row0 + srow) * 1024 + ((sg ^ swz) * 8);
    const unsigned short* gA1 = gA0 + (size_t)64 * 1024;
    const unsigned short* gB0 = whb + (size_t)(col0 + srow) * 1024 + ((sg ^ swz) * 8);
    const unsigned short* gB1 = gB0 + (size_t)64 * 1024;
    unsigned short* lA0 = As + tid * 8;
    unsigned short* lA1 = As + 2048 + tid * 8;
    unsigned short* lB0 = Bs + tid * 8;
    unsigned short* lB1 = Bs + 2048 + tid * 8;

    // fragment read pointers (k-invariant; slot = quad ^ ((row>>1)&3))
    const unsigned short* rA[4];
    const unsigned short* rB[4];
    #pragma unroll
    for (int i = 0; i < 4; ++i) {
        int ra = wy * 64 + i * 16 + l15;
        rA[i] = As + ra * 32 + ((quad ^ ((ra >> 1) & 3)) * 8);
        int rn = wx * 64 + i * 16 + l15;
        rB[i] = Bs + rn * 32 + ((quad ^ ((rn >> 1) & 3)) * 8);
    }

    f32x4 acc[4][4];
    #pragma unroll
    for (int i = 0; i < 4; ++i)
        #pragma unroll
        for (int j = 0; j < 4; ++j)
            acc[i][j] = (f32x4){0.f, 0.f, 0.f, 0.f};

    for (int k0 = 0; k0 < 1024; k0 += 32) {
        __syncthreads();                 // prev iter's frag reads complete
        gl2lds16(gA0 + k0, lA0);
        gl2lds16(gA1 + k0, lA1);
        gl2lds16(gB0 + k0, lB0);
        gl2lds16(gB1 + k0, lB1);
        __syncthreads();                 // DMA drained (barrier waits vmcnt(0))

        bf16x8s af[4], bfv[4];
        #pragma unroll
        for (int i = 0; i < 4; ++i) af[i]  = *(const bf16x8s*)rA[i];
        #pragma unroll
        for (int i = 0; i < 4; ++i) bfv[i] = *(const bf16x8s*)rB[i];
        #pragma unroll
        for (int mt = 0; mt < 4; ++mt)
            #pragma unroll
            for (int nt = 0; nt < 4; ++nt)
                acc[mt][nt] = __builtin_amdgcn_mfma_f32_16x16x32_bf16(af[mt], bfv[nt], acc[mt][nt], 0, 0, 0);
    }

    // epilogue: C/D layout col=lane&15, row=quad*4+r [m89/m91]
    const int colb = col0 + wx * 64 + l15;
    float vwv[4], bv[4];
    #pragma unroll
    for (int nt = 0; nt < 4; ++nt) {
        vwv[nt] = vw[colb + nt * 16];
        bv[nt]  = bias[colb + nt * 16];
    }
    const int rowb = row0 + wy * 64 + quad * 4;
    float* sp = s_part + (size_t)(cb * 2 + wx) * NROWS;
    #pragma unroll
    for (int mt = 0; mt < 4; ++mt) {
        #pragma unroll
        for (int r = 0; r < 4; ++r) {
            float p = 0.f;
            #pragma unroll
            for (int nt = 0; nt < 4; ++nt)
                p += tanh_fast(acc[mt][nt][r] + bv[nt]) * vwv[nt];
            p += __shfl_xor(p, 1);
            p += __shfl_xor(p, 2);
            p += __shfl_xor(p, 4);
            p += __shfl_xor(p, 8);
            if (l15 == 0) sp[rowb + mt * 16 + r] = p;
        }
    }
}

// ---------- kernel 2b: fp32-A fallback (inline pack), only if ws too small ----------
__global__ __launch_bounds__(256) void gemm_f32_kernel(const float* __restrict__ hmat,
                                                       const unsigned short* __restrict__ whb,
                                                       const float* __restrict__ bias,
                                                       const float* __restrict__ vw,
                                                       float* __restrict__ s_part) {
    __shared__ __align__(16) unsigned short As[4096];
    __shared__ __align__(16) unsigned short Bs[4096];
    const int tid = threadIdx.x;
    int rb, cb;
    block_map(blockIdx.x, rb, cb);
    const int wave = tid >> 6;
    const int lane = tid & 63;
    const int quad = lane >> 4;
    const int l15  = lane & 15;
    const int wy   = wave >> 1;
    const int wx   = wave & 1;
    const int row0 = rb * BM;
    const int col0 = cb * BN;
    const int srow = tid >> 2;
    const int sg   = tid & 3;
    const int swz  = (srow >> 1) & 3;
    const float*          gA0 = hmat + (size_t)(row0 + srow)      * 1024 + sg * 8;
    const float*          gA1 = hmat + (size_t)(row0 + srow + 64) * 1024 + sg * 8;
    const unsigned short* gB0 = whb  + (size_t)(col0 + srow)      * 1024 + ((sg ^ swz) * 8);
    unsigned short* wA0 = As + srow * 32 + ((sg ^ swz) * 8);
    unsigned short* wA1 = wA0 + 64 * 32;
    unsigned short* lB0 = Bs + tid * 8;
    const unsigned short* rA[4];
    const unsigned short* rB[4];
    #pragma unroll
    for (int i = 0; i < 4; ++i) {
        int ra = wy * 64 + i * 16 + l15;
        rA[i] = As + ra * 32 + ((quad ^ ((ra >> 1) & 3)) * 8);
        int rn = wx * 64 + i * 16 + l15;
        rB[i] = Bs + rn * 32 + ((quad ^ ((rn >> 1) & 3)) * 8);
    }
    f32x4 acc[4][4];
    #pragma unroll
    for (int i = 0; i < 4; ++i)
        #pragma unroll
        for (int j = 0; j < 4; ++j)
            acc[i][j] = (f32x4){0.f, 0.f, 0.f, 0.f};
    for (int k0 = 0; k0 < 1024; k0 += 32) {
        float4 va0 = *(const float4*)(gA0 + k0);
        float4 va1 = *(const float4*)(gA0 + k0 + 4);
        float4 va2 = *(const float4*)(gA1 + k0);
        float4 va3 = *(const float4*)(gA1 + k0 + 4);
        __syncthreads();
        gl2lds16(gB0 + k0, lB0);
        gl2lds16(gB0 + 65536 + k0, lB0 + 2048);
        uint4 pa0, pa1;
        pa0.x = pack2bf(va0.x, va0.y); pa0.y = pack2bf(va0.z, va0.w);
        pa0.z = pack2bf(va1.x, va1.y); pa0.w = pack2bf(va1.z, va1.w);
        pa1.x = pack2bf(va2.x, va2.y); pa1.y = pack2bf(va2.z, va2.w);
        pa1.z = pack2bf(va3.x, va3.y); pa1.w = pack2bf(va3.z, va3.w);
        *(uint4*)wA0 = pa0;
        *(uint4*)wA1 = pa1;
        __syncthreads();
        bf16x8s af[4], bfv[4];
        #pragma unroll
        for (int i = 0; i < 4; ++i) af[i]  = *(const bf16x8s*)rA[i];
        #pragma unroll
        for (int i = 0; i < 4; ++i) bfv[i] = *(const bf16x8s*)rB[i];
        #pragma unroll
        for (int mt = 0; mt < 4; ++mt)
            #pragma unroll
            for (int nt = 0; nt < 4; ++nt)
                acc[mt][nt] = __builtin_amdgcn_mfma_f32_16x16x32_bf16(af[mt], bfv[nt], acc[mt][nt], 0, 0, 0);
    }
    const int colb = col0 + wx * 64 + l15;
    float vwv[4], bv[4];
    #pragma unroll
    for (int nt = 0; nt < 4; ++nt) {
        vwv[nt] = vw[colb + nt * 16];
        bv[nt]  = bias[colb + nt * 16];
    }
    const int rowb = row0 + wy * 64 + quad * 4;
    float* sp = s_part + (size_t)(cb * 2 + wx) * NROWS;
    #pragma unroll
    for (int mt = 0; mt < 4; ++mt) {
        #pragma unroll
        for (int r = 0; r < 4; ++r) {
            float p = 0.f;
            #pragma unroll
            for (int nt = 0; nt < 4; ++nt)
                p += tanh_fast(acc[mt][nt][r] + bv[nt]) * vwv[nt];
            p += __shfl_xor(p, 1);
            p += __shfl_xor(p, 2);
            p += __shfl_xor(p, 4);
            p += __shfl_xor(p, 8);
            if (l15 == 0) sp[rowb + mt * 16 + r] = p;
        }
    }
}

// ---------- kernel 3: sum partials + masked softmax; also zeroes d_out ----------
__global__ __launch_bounds__(256) void softmax_kernel(const float* __restrict__ s_part,
                                                      const int* __restrict__ mask,
                                                      float* __restrict__ a_buf,
                                                      float* __restrict__ out) {
    const int b    = blockIdx.x;
    const int t    = threadIdx.x;
    const int wave = t >> 6;
    const int lane = t & 63;
    // zero the output slice this batch will atomically accumulate into (kernel 4)
    ((float4*)(out + b * 1024))[t] = (float4){0.f, 0.f, 0.f, 0.f};
    __shared__ float redm[4];
    __shared__ float reds[4];
    float sv[8];
    float mx = -3.0e38f;
    #pragma unroll
    for (int j = 0; j < 8; ++j) {
        int l = t + j * 256;
        float v = 0.f;
        #pragma unroll
        for (int c = 0; c < 16; ++c)
            v += s_part[(size_t)c * NROWS + b * 2048 + l];
        if (mask[b * 2048 + l] == 0) v -= 10000.f;
        sv[j] = v;
        mx = fmaxf(mx, v);
    }
    #pragma unroll
    for (int off = 32; off; off >>= 1) mx = fmaxf(mx, __shfl_xor(mx, off));
    if (lane == 0) redm[wave] = mx;
    __syncthreads();
    mx = fmaxf(fmaxf(redm[0], redm[1]), fmaxf(redm[2], redm[3]));
    float sum = 0.f;
    #pragma unroll
    for (int j = 0; j < 8; ++j) {
        sv[j] = __expf(sv[j] - mx);
        sum += sv[j];
    }
    #pragma unroll
    for (int off = 32; off; off >>= 1) sum += __shfl_xor(sum, off);
    if (lane == 0) reds[wave] = sum;
    __syncthreads();
    sum = reds[0] + reds[1] + reds[2] + reds[3];
    float inv = 1.f / sum;
    #pragma unroll
    for (int j = 0; j < 8; ++j)
        a_buf[b * 2048 + t + j * 256] = sv[j] * inv;
}

// ---------- kernel 4a: r[b,i] = sum_l a[b,l]*h[b,l,i], bf16 h (halved read) ----------
__global__ __launch_bounds__(256) void r_bf16_kernel(const unsigned short* __restrict__ hb,
                                                     const float* __restrict__ a_buf,
                                                     float* __restrict__ out) {
    const int b  = blockIdx.x >> 5;
    const int lc = blockIdx.x & 31;
    const int t  = threadIdx.x;
    __shared__ float aw[64];
    if (t < 64) aw[t] = a_buf[b * 2048 + lc * 64 + t];
    __syncthreads();
    const uint2* hp = (const uint2*)(hb + (size_t)(b * 2048 + lc * 64) * 1024) + t;
    float a0 = 0.f, a1 = 0.f, a2 = 0.f, a3 = 0.f;
    #pragma unroll 8
    for (int l = 0; l < 64; ++l) {
        uint2 v = hp[(size_t)l * 256];
        float av = aw[l];
        a0 += av * __uint_as_float(v.x << 16);
        a1 += av * __uint_as_float(v.x & 0xffff0000u);
        a2 += av * __uint_as_float(v.y << 16);
        a3 += av * __uint_as_float(v.y & 0xffff0000u);
    }
    float* op = out + b * 1024 + t * 4;
    atomicAdd(op + 0, a0);
    atomicAdd(op + 1, a1);
    atomicAdd(op + 2, a2);
    atomicAdd(op + 3, a3);
}

// ---------- kernel 4b: fp32 fallback ----------
__global__ __launch_bounds__(256) void r_f32_kernel(const float* __restrict__ hmat,
                                                    const float* __restrict__ a_buf,
                                                    float* __restrict__ out) {
    const int b  = blockIdx.x >> 5;
    const int lc = blockIdx.x & 31;
    const int t  = threadIdx.x;
    __shared__ float aw[64];
    if (t < 64) aw[t] = a_buf[b * 2048 + lc * 64 + t];
    __syncthreads();
    const float4* hp = (const float4*)hmat + (size_t)(b * 2048 + lc * 64) * 256;
    float ax = 0.f, ay = 0.f, az = 0.f, aq = 0.f;
    #pragma unroll 8
    for (int l = 0; l < 64; ++l) {
        float4 hv = hp[(size_t)l * 256 + t];
        float av = aw[l];
        ax += av * hv.x; ay += av * hv.y; az += av * hv.z; aq += av * hv.w;
    }
    float* op = out + b * 1024 + t * 4;
    atomicAdd(op + 0, ax);
    atomicAdd(op + 1, ay);
    atomicAdd(op + 2, az);
    atomicAdd(op + 3, aq);
}

// ---------- launch (4 dispatches, no memsets) ----------
extern "C" void kernel_launch(void* const* d_in, const int* in_sizes, int n_in,
                              void* d_out, int out_size, void* d_ws, size_t ws_size,
                              hipStream_t stream) {
    const float* h    = (const float*)d_in[0];
    const int*   mask = (const int*)d_in[1];
    const float* ln_w = (const float*)d_in[2];
    const float* ln_b = (const float*)d_in[3];
    const float* v_w  = (const float*)d_in[4];
    const float* vq   = (const float*)d_in[5];
    float* out = (float*)d_out;

    char* ws = (char*)d_ws;
    unsigned short* whb = (unsigned short*)(ws + WHB_OFF);
    float* bias         = (float*)(ws + BIAS_OFF);
    float* s_part       = (float*)(ws + SPART_OFF);
    float* a_buf        = (float*)(ws + ABUF_OFF);
    unsigned short* hb  = (unsigned short*)(ws + HB_OFF);

    const bool use_bf16_h = (ws_size >= WS_NEED_BF16);

    if (use_bf16_h) {
        prep_kernel<<<1024 + 32768, 256, 0, stream>>>(ln_w, ln_b, vq, h, whb, bias, hb);
        gemm32_kernel<<<(NROWS / BM) * (HID / BN), 256, 0, stream>>>(hb, whb, bias, v_w, s_part);
        softmax_kernel<<<BATCH, 256, 0, stream>>>(s_part, mask, a_buf, out);
        r_bf16_kernel<<<BATCH * 32, 256, 0, stream>>>(hb, a_buf, out);
    } else {
        prep_kernel<<<1024, 256, 0, stream>>>(ln_w, ln_b, vq, h, whb, bias, hb);
        gemm_f32_kernel<<<(NROWS / BM) * (HID / BN), 256, 0, stream>>>(h, whb, bias, v_w, s_part);
        softmax_kernel<<<BATCH, 256, 0, stream>>>(s_part, mask, a_buf, out);
        r_f32_kernel<<<BATCH * 32, 256, 0, stream>>>(h, a_buf, out);
    }
}

// Round 5
// 562.895 us; speedup vs baseline: 1.1246x; 1.0315x over previous
//
#include <hip/hip_runtime.h>
#include <hip/hip_bf16.h>

// ---------- types ----------
typedef short  bf16x8s __attribute__((ext_vector_type(8)));  // 8 bf16 (4 VGPRs)
typedef float  f32x4   __attribute__((ext_vector_type(4)));  // 4 fp32 acc

#define BATCH 32
#define SEQL  2048
#define NROWS (BATCH * SEQL)   // 65536
#define IN    1024
#define HID   1024

// workspace layout
#define WHB_OFF   0u          // 2 MB   bf16 W_h
#define BIAS_OFF  0x200000u   // 4 KB
#define SPART_OFF 0x210000u   // 4 MB   s partials [16][65536]
#define ABUF_OFF  0x610000u   // 256 KB softmax weights
#define HB_OFF    0x650000u   // 128 MB bf16 h
#define WS_NEED_BF16 ((size_t)HB_OFF + (size_t)NROWS * IN * 2)

// pack two fp32 -> two bf16 (round-up-on-half via +0x8000, v_perm byte select)
__device__ __forceinline__ unsigned int pack2bf(float f0, float f1) {
    unsigned int u0 = __float_as_uint(f0) + 0x8000u;
    unsigned int u1 = __float_as_uint(f1) + 0x8000u;
    return __builtin_amdgcn_perm(u1, u0, 0x07060302u);
}

__device__ __forceinline__ float tanh_fast(float x) {
    float xc = fminf(fmaxf(x, -15.f), 15.f);
    float t  = __builtin_amdgcn_exp2f(xc * 2.8853900817779268f); // e^(2x)
    return (t - 1.f) * __builtin_amdgcn_rcpf(t + 1.f);
}

// async 16B global->LDS (DMA; LDS dest = wave-uniform base + lane*16)
__device__ __forceinline__ void gl2lds16(const void* g, void* l) {
    __builtin_amdgcn_global_load_lds(
        (const __attribute__((address_space(1))) unsigned int*)g,
        (__attribute__((address_space(3))) unsigned int*)l, 16, 0, 0);
}

// XCD-locality swizzle: the 8 cb-siblings of a row-block share bi%8 -> same XCD
// (round-robin) -> A row-block L2-resident across re-reads. [R2: FETCH 1.06GB->92MB]
__device__ __forceinline__ void block_map(int bi, int& rb, int& cb) {
    int xcd  = bi & 7;
    int slot = bi >> 3;
    rb = xcd + 8 * (slot >> 3);
    cb = slot & 7;
}

// ---------- kernel 1: fused [W_h->bf16 + bias] (blocks 0..1023) and h->bf16 (rest) ----
__global__ __launch_bounds__(256) void prep_kernel(const float* __restrict__ ln_w,
                                                   const float* __restrict__ ln_b,
                                                   const float* __restrict__ vq,
                                                   const float* __restrict__ h,
                                                   unsigned short* __restrict__ whb,
                                                   float* __restrict__ bias,
                                                   unsigned short* __restrict__ hb) {
    const int bi = blockIdx.x;
    const int t  = threadIdx.x;
    if (bi < 1024) {
        const int n = bi;
        const int wave = t >> 6;
        const int lane = t & 63;
        float4 v = ((const float4*)(ln_w + (size_t)n * 2048))[t];
        uint2 pk;
        pk.x = pack2bf(v.x, v.y);
        pk.y = pack2bf(v.z, v.w);
        *(uint2*)(whb + (size_t)n * 1024 + t * 4) = pk;
        const float* wrow = ln_w + (size_t)n * 2048 + 1024;
        float s = 0.f;
        #pragma unroll
        for (int j = 0; j < 4; ++j) {
            int k = t + j * 256;
            s += wrow[k] * vq[k];
        }
        #pragma unroll
        for (int off = 32; off; off >>= 1) s += __shfl_xor(s, off);
        __shared__ float red[4];
        if (lane == 0) red[wave] = s;
        __syncthreads();
        if (t == 0) bias[n] = ln_b[n] + red[0] + red[1] + red[2] + red[3];
    } else {
        size_t idx = ((size_t)(bi - 1024) * 256 + t) * 8;
        float4 a = *(const float4*)(h + idx);
        float4 b = *(const float4*)(h + idx + 4);
        uint4 p;
        p.x = pack2bf(a.x, a.y); p.y = pack2bf(a.z, a.w);
        p.z = pack2bf(b.x, b.y); p.w = pack2bf(b.z, b.w);
        *(uint4*)(hb + idx) = p;
    }
}

// ---------- kernel 2: bf16 GEMM, BM=256 x BN=128, BK=32, 8 waves ----------
// Per-wave structure identical to the R2/R4-proven 64x64 4x4-acc kernel; the block
// just carries 4 row-bands (wy 0..3). 2x MFMA per barrier at same VGPR, LDS 24KB.
// epilogue: s_part[cb*2+wx][row] = partial of sum_cols tanh(pre+bias)*v_w
__global__ __launch_bounds__(512) void gemm256_kernel(const unsigned short* __restrict__ hb,
                                                      const unsigned short* __restrict__ whb,
                                                      const float* __restrict__ bias,
                                                      const float* __restrict__ vw,
                                                      float* __restrict__ s_part) {
    __shared__ __align__(16) unsigned short As[8192]; // 16 KB: 256 rows x 32 shorts
    __shared__ __align__(16) unsigned short Bs[4096]; // 8 KB : 128 rows x 32 shorts

    const int tid = threadIdx.x;
    int rb, cb;
    block_map(blockIdx.x, rb, cb);
    const int wave = tid >> 6;
    const int lane = tid & 63;
    const int quad = lane >> 4;
    const int l15  = lane & 15;
    const int wy   = wave >> 1;          // 0..3 row band
    const int wx   = wave & 1;           // 0..1 col band
    const int row0 = rb * 256;
    const int col0 = cb * 128;

    // DMA staging (proven layout: row stride 32 shorts; slot sg holds k-group
    // sg^swz(row), swz=(row>>1)&3; LDS dest lane-linear tid*16B).
    // 512 threads: A issue0 rows 0..127, issue1 rows 128..255; B one issue rows 0..127.
    const int srow = tid >> 2;           // 0..127
    const int sg   = tid & 3;
    const int swz  = (srow >> 1) & 3;
    const unsigned short* gA0 = hb  + (size_t)(row0 + srow) * 1024 + ((sg ^ swz) * 8);
    const unsigned short* gA1 = gA0 + (size_t)128 * 1024;
    const unsigned short* gB0 = whb + (size_t)(col0 + srow) * 1024 + ((sg ^ swz) * 8);
    unsigned short* lA0 = As + tid * 8;          // bytes [0, 8192)
    unsigned short* lA1 = As + 4096 + tid * 8;   // bytes [8192, 16384)
    unsigned short* lB0 = Bs + tid * 8;          // bytes [0, 8192)

    // fragment read pointers (k-invariant; slot = quad ^ ((row>>1)&3))
    const unsigned short* rA[4];
    const unsigned short* rB[4];
    #pragma unroll
    for (int i = 0; i < 4; ++i) {
        int ra = wy * 64 + i * 16 + l15;         // 0..255
        rA[i] = As + ra * 32 + ((quad ^ ((ra >> 1) & 3)) * 8);
        int rn = wx * 64 + i * 16 + l15;         // 0..127
        rB[i] = Bs + rn * 32 + ((quad ^ ((rn >> 1) & 3)) * 8);
    }

    f32x4 acc[4][4];
    #pragma unroll
    for (int i = 0; i < 4; ++i)
        #pragma unroll
        for (int j = 0; j < 4; ++j)
            acc[i][j] = (f32x4){0.f, 0.f, 0.f, 0.f};

    for (int k0 = 0; k0 < 1024; k0 += 32) {
        __syncthreads();                 // prev iter's frag reads complete
        gl2lds16(gA0 + k0, lA0);
        gl2lds16(gA1 + k0, lA1);
        gl2lds16(gB0 + k0, lB0);
        __syncthreads();                 // DMA drained (barrier waits vmcnt(0))

        bf16x8s af[4], bfv[4];
        #pragma unroll
        for (int i = 0; i < 4; ++i) af[i]  = *(const bf16x8s*)rA[i];
        #pragma unroll
        for (int i = 0; i < 4; ++i) bfv[i] = *(const bf16x8s*)rB[i];
        #pragma unroll
        for (int mt = 0; mt < 4; ++mt)
            #pragma unroll
            for (int nt = 0; nt < 4; ++nt)
                acc[mt][nt] = __builtin_amdgcn_mfma_f32_16x16x32_bf16(af[mt], bfv[nt], acc[mt][nt], 0, 0, 0);
    }

    // epilogue: C/D layout col=lane&15, row=quad*4+r [m89/m91]
    const int colb = col0 + wx * 64 + l15;
    float vwv[4], bv[4];
    #pragma unroll
    for (int nt = 0; nt < 4; ++nt) {
        vwv[nt] = vw[colb + nt * 16];
        bv[nt]  = bias[colb + nt * 16];
    }
    const int rowb = row0 + wy * 64 + quad * 4;
    float* sp = s_part + (size_t)(cb * 2 + wx) * NROWS;
    #pragma unroll
    for (int mt = 0; mt < 4; ++mt) {
        #pragma unroll
        for (int r = 0; r < 4; ++r) {
            float p = 0.f;
            #pragma unroll
            for (int nt = 0; nt < 4; ++nt)
                p += tanh_fast(acc[mt][nt][r] + bv[nt]) * vwv[nt];
            p += __shfl_xor(p, 1);
            p += __shfl_xor(p, 2);
            p += __shfl_xor(p, 4);
            p += __shfl_xor(p, 8);
            if (l15 == 0) sp[rowb + mt * 16 + r] = p;
        }
    }
}

// ---------- kernel 2b: fp32-A fallback (inline pack), only if ws too small ----------
__global__ __launch_bounds__(256) void gemm_f32_kernel(const float* __restrict__ hmat,
                                                       const unsigned short* __restrict__ whb,
                                                       const float* __restrict__ bias,
                                                       const float* __restrict__ vw,
                                                       float* __restrict__ s_part) {
    __shared__ __align__(16) unsigned short As[4096];
    __shared__ __align__(16) unsigned short Bs[4096];
    const int tid = threadIdx.x;
    int rb, cb;
    block_map(blockIdx.x, rb, cb);
    const int wave = tid >> 6;
    const int lane = tid & 63;
    const int quad = lane >> 4;
    const int l15  = lane & 15;
    const int wy   = wave >> 1;
    const int wx   = wave & 1;
    const int row0 = rb * 128;
    const int col0 = cb * 128;
    const int srow = tid >> 2;
    const int sg   = tid & 3;
    const int swz  = (srow >> 1) & 3;
    const float*          gA0 = hmat + (size_t)(row0 + srow)      * 1024 + sg * 8;
    const float*          gA1 = hmat + (size_t)(row0 + srow + 64) * 1024 + sg * 8;
    const unsigned short* gB0 = whb  + (size_t)(col0 + srow)      * 1024 + ((sg ^ swz) * 8);
    unsigned short* wA0 = As + srow * 32 + ((sg ^ swz) * 8);
    unsigned short* wA1 = wA0 + 64 * 32;
    unsigned short* lB0 = Bs + tid * 8;
    const unsigned short* rA[4];
    const unsigned short* rB[4];
    #pragma unroll
    for (int i = 0; i < 4; ++i) {
        int ra = wy * 64 + i * 16 + l15;
        rA[i] = As + ra * 32 + ((quad ^ ((ra >> 1) & 3)) * 8);
        int rn = wx * 64 + i * 16 + l15;
        rB[i] = Bs + rn * 32 + ((quad ^ ((rn >> 1) & 3)) * 8);
    }
    f32x4 acc[4][4];
    #pragma unroll
    for (int i = 0; i < 4; ++i)
        #pragma unroll
        for (int j = 0; j < 4; ++j)
            acc[i][j] = (f32x4){0.f, 0.f, 0.f, 0.f};
    for (int k0 = 0; k0 < 1024; k0 += 32) {
        float4 va0 = *(const float4*)(gA0 + k0);
        float4 va1 = *(const float4*)(gA0 + k0 + 4);
        float4 va2 = *(const float4*)(gA1 + k0);
        float4 va3 = *(const float4*)(gA1 + k0 + 4);
        __syncthreads();
        gl2lds16(gB0 + k0, lB0);
        gl2lds16(gB0 + 65536 + k0, lB0 + 2048);
        uint4 pa0, pa1;
        pa0.x = pack2bf(va0.x, va0.y); pa0.y = pack2bf(va0.z, va0.w);
        pa0.z = pack2bf(va1.x, va1.y); pa0.w = pack2bf(va1.z, va1.w);
        pa1.x = pack2bf(va2.x, va2.y); pa1.y = pack2bf(va2.z, va2.w);
        pa1.z = pack2bf(va3.x, va3.y); pa1.w = pack2bf(va3.z, va3.w);
        *(uint4*)wA0 = pa0;
        *(uint4*)wA1 = pa1;
        __syncthreads();
        bf16x8s af[4], bfv[4];
        #pragma unroll
        for (int i = 0; i < 4; ++i) af[i]  = *(const bf16x8s*)rA[i];
        #pragma unroll
        for (int i = 0; i < 4; ++i) bfv[i] = *(const bf16x8s*)rB[i];
        #pragma unroll
        for (int mt = 0; mt < 4; ++mt)
            #pragma unroll
            for (int nt = 0; nt < 4; ++nt)
                acc[mt][nt] = __builtin_amdgcn_mfma_f32_16x16x32_bf16(af[mt], bfv[nt], acc[mt][nt], 0, 0, 0);
    }
    const int colb = col0 + wx * 64 + l15;
    float vwv[4], bv[4];
    #pragma unroll
    for (int nt = 0; nt < 4; ++nt) {
        vwv[nt] = vw[colb + nt * 16];
        bv[nt]  = bias[colb + nt * 16];
    }
    const int rowb = row0 + wy * 64 + quad * 4;
    float* sp = s_part + (size_t)(cb * 2 + wx) * NROWS;
    #pragma unroll
    for (int mt = 0; mt < 4; ++mt) {
        #pragma unroll
        for (int r = 0; r < 4; ++r) {
            float p = 0.f;
            #pragma unroll
            for (int nt = 0; nt < 4; ++nt)
                p += tanh_fast(acc[mt][nt][r] + bv[nt]) * vwv[nt];
            p += __shfl_xor(p, 1);
            p += __shfl_xor(p, 2);
            p += __shfl_xor(p, 4);
            p += __shfl_xor(p, 8);
            if (l15 == 0) sp[rowb + mt * 16 + r] = p;
        }
    }
}

// ---------- kernel 3: sum partials + masked softmax; also zeroes d_out ----------
__global__ __launch_bounds__(256) void softmax_kernel(const float* __restrict__ s_part,
                                                      const int* __restrict__ mask,
                                                      float* __restrict__ a_buf,
                                                      float* __restrict__ out) {
    const int b    = blockIdx.x;
    const int t    = threadIdx.x;
    const int wave = t >> 6;
    const int lane = t & 63;
    // zero the output slice this batch will atomically accumulate into (kernel 4)
    ((float4*)(out + b * 1024))[t] = (float4){0.f, 0.f, 0.f, 0.f};
    __shared__ float redm[4];
    __shared__ float reds[4];
    float sv[8];
    float mx = -3.0e38f;
    #pragma unroll
    for (int j = 0; j < 8; ++j) {
        int l = t + j * 256;
        float v = 0.f;
        #pragma unroll
        for (int c = 0; c < 16; ++c)
            v += s_part[(size_t)c * NROWS + b * 2048 + l];
        if (mask[b * 2048 + l] == 0) v -= 10000.f;
        sv[j] = v;
        mx = fmaxf(mx, v);
    }
    #pragma unroll
    for (int off = 32; off; off >>= 1) mx = fmaxf(mx, __shfl_xor(mx, off));
    if (lane == 0) redm[wave] = mx;
    __syncthreads();
    mx = fmaxf(fmaxf(redm[0], redm[1]), fmaxf(redm[2], redm[3]));
    float sum = 0.f;
    #pragma unroll
    for (int j = 0; j < 8; ++j) {
        sv[j] = __expf(sv[j] - mx);
        sum += sv[j];
    }
    #pragma unroll
    for (int off = 32; off; off >>= 1) sum += __shfl_xor(sum, off);
    if (lane == 0) reds[wave] = sum;
    __syncthreads();
    sum = reds[0] + reds[1] + reds[2] + reds[3];
    float inv = 1.f / sum;
    #pragma unroll
    for (int j = 0; j < 8; ++j)
        a_buf[b * 2048 + t + j * 256] = sv[j] * inv;
}

// ---------- kernel 4a: r[b,i] = sum_l a[b,l]*h[b,l,i], bf16 h (halved read) ----------
__global__ __launch_bounds__(256) void r_bf16_kernel(const unsigned short* __restrict__ hb,
                                                     const float* __restrict__ a_buf,
                                                     float* __restrict__ out) {
    const int b  = blockIdx.x >> 5;
    const int lc = blockIdx.x & 31;
    const int t  = threadIdx.x;
    __shared__ float aw[64];
    if (t < 64) aw[t] = a_buf[b * 2048 + lc * 64 + t];
    __syncthreads();
    const uint2* hp = (const uint2*)(hb + (size_t)(b * 2048 + lc * 64) * 1024) + t;
    float a0 = 0.f, a1 = 0.f, a2 = 0.f, a3 = 0.f;
    #pragma unroll 8
    for (int l = 0; l < 64; ++l) {
        uint2 v = hp[(size_t)l * 256];
        float av = aw[l];
        a0 += av * __uint_as_float(v.x << 16);
        a1 += av * __uint_as_float(v.x & 0xffff0000u);
        a2 += av * __uint_as_float(v.y << 16);
        a3 += av * __uint_as_float(v.y & 0xffff0000u);
    }
    float* op = out + b * 1024 + t * 4;
    atomicAdd(op + 0, a0);
    atomicAdd(op + 1, a1);
    atomicAdd(op + 2, a2);
    atomicAdd(op + 3, a3);
}

// ---------- kernel 4b: fp32 fallback ----------
__global__ __launch_bounds__(256) void r_f32_kernel(const float* __restrict__ hmat,
                                                    const float* __restrict__ a_buf,
                                                    float* __restrict__ out) {
    const int b  = blockIdx.x >> 5;
    const int lc = blockIdx.x & 31;
    const int t  = threadIdx.x;
    __shared__ float aw[64];
    if (t < 64) aw[t] = a_buf[b * 2048 + lc * 64 + t];
    __syncthreads();
    const float4* hp = (const float4*)hmat + (size_t)(b * 2048 + lc * 64) * 256;
    float ax = 0.f, ay = 0.f, az = 0.f, aq = 0.f;
    #pragma unroll 8
    for (int l = 0; l < 64; ++l) {
        float4 hv = hp[(size_t)l * 256 + t];
        float av = aw[l];
        ax += av * hv.x; ay += av * hv.y; az += av * hv.z; aq += av * hv.w;
    }
    float* op = out + b * 1024 + t * 4;
    atomicAdd(op + 0, ax);
    atomicAdd(op + 1, ay);
    atomicAdd(op + 2, az);
    atomicAdd(op + 3, aq);
}

// ---------- launch (4 dispatches, no memsets) ----------
extern "C" void kernel_launch(void* const* d_in, const int* in_sizes, int n_in,
                              void* d_out, int out_size, void* d_ws, size_t ws_size,
                              hipStream_t stream) {
    const float* h    = (const float*)d_in[0];
    const int*   mask = (const int*)d_in[1];
    const float* ln_w = (const float*)d_in[2];
    const float* ln_b = (const float*)d_in[3];
    const float* v_w  = (const float*)d_in[4];
    const float* vq   = (const float*)d_in[5];
    float* out = (float*)d_out;

    char* ws = (char*)d_ws;
    unsigned short* whb = (unsigned short*)(ws + WHB_OFF);
    float* bias         = (float*)(ws + BIAS_OFF);
    float* s_part       = (float*)(ws + SPART_OFF);
    float* a_buf        = (float*)(ws + ABUF_OFF);
    unsigned short* hb  = (unsigned short*)(ws + HB_OFF);

    const bool use_bf16_h = (ws_size >= WS_NEED_BF16);

    if (use_bf16_h) {
        prep_kernel<<<1024 + 32768, 256, 0, stream>>>(ln_w, ln_b, vq, h, whb, bias, hb);
        gemm256_kernel<<<(NROWS / 256) * (HID / 128), 512, 0, stream>>>(hb, whb, bias, v_w, s_part);
        softmax_kernel<<<BATCH, 256, 0, stream>>>(s_part, mask, a_buf, out);
        r_bf16_kernel<<<BATCH * 32, 256, 0, stream>>>(hb, a_buf, out);
    } else {
        prep_kernel<<<1024, 256, 0, stream>>>(ln_w, ln_b, vq, h, whb, bias, hb);
        gemm_f32_kernel<<<(NROWS / 128) * (HID / 128), 256, 0, stream>>>(h, whb, bias, v_w, s_part);
        softmax_kernel<<<BATCH, 256, 0, stream>>>(s_part, mask, a_buf, out);
        r_f32_kernel<<<BATCH * 32, 256, 0, stream>>>(h, a_buf, out);
    }
}